// Round 1
// baseline (3062.989 us; speedup 1.0000x reference)
//
#include <hip/hip_runtime.h>
#include <hip/hip_bf16.h>

// Problem constants
#define B_ 64
#define S_ 512
#define I_ 128
#define H_ 1024
#define O_ 128
#define ALPHA 0.1f

typedef __attribute__((ext_vector_type(8))) short short8;
typedef __attribute__((ext_vector_type(4))) float f32x4;

__device__ __forceinline__ unsigned short f2bf(float f) {
    unsigned int b = __float_as_uint(f);
    b += 0x7fffu + ((b >> 16) & 1u);   // RNE; inputs are finite
    return (unsigned short)(b >> 16);
}
__device__ __forceinline__ float bf2f(unsigned short u) {
    return __uint_as_float(((unsigned int)u) << 16);
}
__device__ __forceinline__ float sigmoidf_(float v) {
    return 1.0f / (1.0f + __expf(-v));
}

// ---------------------------------------------------------------------------
// K1: U[b,t,j] = ALPHA * (x[b,t,:] . W_ih[j,:]) + 0.01*noise[t,b,j]
// stored into the hidden region of d_out at [bt, j].
// Tile: 64 bt-rows x 64 j, K=128. x fp32 in LDS, W_ih bf16 in LDS.
// ---------------------------------------------------------------------------
__global__ __launch_bounds__(256) void k1_precompute_u(
    const float* __restrict__ x, const float* __restrict__ Wih,
    const float* __restrict__ noise, float* __restrict__ U) {
    __shared__ float xs[64 * 132];
    __shared__ unsigned short wl[64 * 132];
    const int tid = threadIdx.x;
    const int R0 = blockIdx.x * 64;
    const int J0 = blockIdx.y * 64;
#pragma unroll
    for (int i = 0; i < 8; ++i) {
        int f = i * 1024 + tid * 4;
        float4 v = *(const float4*)(x + (size_t)R0 * 128 + f);
        int row = f >> 7, col = f & 127;
        *(float4*)(xs + row * 132 + col) = v;
    }
#pragma unroll
    for (int i = 0; i < 8; ++i) {
        int f = i * 1024 + tid * 4;
        float4 v = *(const float4*)(Wih + (size_t)J0 * 128 + f);
        int row = f >> 7, col = f & 127;
        uint2 pk;
        pk.x = (unsigned)f2bf(v.x) | ((unsigned)f2bf(v.y) << 16);
        pk.y = (unsigned)f2bf(v.z) | ((unsigned)f2bf(v.w) << 16);
        *(uint2*)(wl + row * 132 + col) = pk;
    }
    __syncthreads();
    const int btq = (tid >> 4) * 4;   // 4 consecutive bt rows
    const int jb = tid & 15;          // j strided by 16
    float acc[4][4];
#pragma unroll
    for (int a = 0; a < 4; ++a)
#pragma unroll
        for (int c = 0; c < 4; ++c) acc[a][c] = 0.f;
    for (int k = 0; k < 128; k += 4) {
        float4 xa[4];
#pragma unroll
        for (int a = 0; a < 4; ++a) xa[a] = *(const float4*)(xs + (btq + a) * 132 + k);
#pragma unroll
        for (int c = 0; c < 4; ++c) {
            uint2 w2 = *(const uint2*)(wl + (jb + 16 * c) * 132 + k);
            float w0 = bf2f((unsigned short)(w2.x & 0xffffu));
            float w1 = bf2f((unsigned short)(w2.x >> 16));
            float w2f = bf2f((unsigned short)(w2.y & 0xffffu));
            float w3 = bf2f((unsigned short)(w2.y >> 16));
#pragma unroll
            for (int a = 0; a < 4; ++a)
                acc[a][c] += xa[a].x * w0 + xa[a].y * w1 + xa[a].z * w2f + xa[a].w * w3;
        }
    }
#pragma unroll
    for (int a = 0; a < 4; ++a) {
        int bt = R0 + btq + a;
        int b = bt >> 9, t = bt & 511;
#pragma unroll
        for (int c = 0; c < 4; ++c) {
            int j = J0 + jb + 16 * c;
            float u = ALPHA * acc[a][c] + 0.01f * noise[((size_t)t * 64 + b) * 1024 + j];
            U[(size_t)bt * 1024 + j] = u;
        }
    }
}

// ---------------------------------------------------------------------------
// K2: init exchange buffer E[0] with swizzled bf16 sigmoid(h0); zero flags.
// E layout (per buffer, per group g): [kb(32)][q(4)][r(16)][i(8)] bf16
//   element (b=g*16+r, k=kb*32+q*8+i). 32KB per group, 128KB per buffer.
// ---------------------------------------------------------------------------
__global__ __launch_bounds__(256) void k2_init(
    const float* __restrict__ h0, unsigned long long* __restrict__ Ebuf,
    unsigned int* __restrict__ flags) {
    const int tid = threadIdx.x;
    const int b = blockIdx.x;
    const int g = b >> 4, r = b & 15;
    const int k0 = tid * 4;
    const int kb = k0 >> 5, q = (k0 >> 3) & 3, i0 = k0 & 7;
    unsigned long long pk = 0;
#pragma unroll
    for (int j = 0; j < 4; ++j) {
        float s = sigmoidf_(h0[(size_t)b * 1024 + k0 + j]);
        pk |= ((unsigned long long)f2bf(s)) << (16 * j);
    }
    size_t byteoff = (size_t)g * 32768 + (size_t)(kb * 64 + q * 16 + r) * 16 + (size_t)i0 * 2;
    __hip_atomic_store(Ebuf + (byteoff >> 3), pk, __ATOMIC_RELAXED, __HIP_MEMORY_SCOPE_AGENT);
    if (b == 0 && tid < 64)
        __hip_atomic_store(flags + tid, 0u, __ATOMIC_RELAXED, __HIP_MEMORY_SCOPE_AGENT);
}

// ---------------------------------------------------------------------------
// K3: the recurrence. 64 WGs = 4 batch-groups x 16 j-groups; block 256.
// Each WG: 16 b x 64 j tile. W_hh slice lives in registers as bf16 B-frags.
// K split over 4 waves (8 k-blocks each), LDS reduction of partials.
// Exchange of sigma(h) via global ping-pong buffer, agent-scope atomics.
// Per-group 16-flag barrier, one per step.
// ---------------------------------------------------------------------------
__global__ __launch_bounds__(256, 1) void k3_rnn(
    const float* __restrict__ Whh, const float* __restrict__ h0,
    const float* __restrict__ sgnv, float* __restrict__ hidden,
    unsigned long long* __restrict__ Ebuf, unsigned int* __restrict__ flags) {
    __shared__ float zred[4 * 1040];   // [wave][b(16) stride 65][j(64)]
    const int tid = threadIdx.x;
    const int wave = tid >> 6, lane = tid & 63;
    const int wg = blockIdx.x;
    const int grp = wg >> 4;   // batch group 0..3
    const int Jg = wg & 15;    // j group 0..15
    const int jl = lane & 15, q = lane >> 4;

    // Persistent W_hh B-fragments: wfrag[jsub][kbl]
    // B[k][n] = Whh[n][k]; lane: n = jl, k = (wave*8+kbl)*32 + q*8 + i
    short8 wfrag[4][8];
#pragma unroll
    for (int jsub = 0; jsub < 4; ++jsub) {
        int jg = Jg * 64 + jsub * 16 + jl;
#pragma unroll
        for (int kbl = 0; kbl < 8; ++kbl) {
            int k = (wave * 8 + kbl) * 32 + q * 8;
            const float* wp = Whh + (size_t)jg * 1024 + k;
            float4 v0 = *(const float4*)(wp);
            float4 v1 = *(const float4*)(wp + 4);
            short8 f;
            f[0] = (short)f2bf(v0.x); f[1] = (short)f2bf(v0.y);
            f[2] = (short)f2bf(v0.z); f[3] = (short)f2bf(v0.w);
            f[4] = (short)f2bf(v1.x); f[5] = (short)f2bf(v1.y);
            f[6] = (short)f2bf(v1.z); f[7] = (short)f2bf(v1.w);
            wfrag[jsub][kbl] = f;
        }
    }

    // Per-thread epilogue ownership: (b = grp*16 + bl, j = Jg*64 + jq*4 + c)
    const int bl = tid & 15;
    const int jq = tid >> 4;
    const int bg = grp * 16 + bl;
    const int jbase = Jg * 64 + jq * 4;
    float hold[4], sgn[4];
#pragma unroll
    for (int c = 0; c < 4; ++c) {
        hold[c] = h0[(size_t)bg * 1024 + jbase + c];
        sgn[c] = sgnv[jbase + c];
    }
    float* hidrow = hidden + (size_t)bg * (512 * 1024) + jbase;

    // E write slot for this thread's 4 consecutive j (= k of next step)
    const int kbw = jbase >> 5;
    const int qqw = (jbase >> 3) & 3;
    const int i0w = jbase & 7;   // 0 or 4
    const size_t ewoff = (((size_t)grp * 32768 +
                           (size_t)(kbw * 64 + qqw * 16 + bl) * 16 + (size_t)i0w * 2) >> 3);

    const size_t eload_base = (size_t)grp * 4096 + (size_t)lane * 2;  // ull units
    const int fl_idx = grp * 16 + (lane & 15);

#pragma unroll 1
    for (int t = 0; t < 512; ++t) {
        // Wait for s^(t) (flags >= t); t=0 passes immediately (flags zeroed).
        if (wave == 0) {
            for (;;) {
                unsigned int v = __hip_atomic_load(flags + fl_idx, __ATOMIC_ACQUIRE,
                                                   __HIP_MEMORY_SCOPE_AGENT);
                if (__all((int)(v >= (unsigned int)t))) break;
            }
        }
        __syncthreads();
        const int p = t & 1;
        const unsigned long long* Ep = Ebuf + (size_t)p * 16384 + eload_base;
        unsigned long long a0[8], a1[8];
#pragma unroll
        for (int kbl = 0; kbl < 8; ++kbl) {
            size_t off = (size_t)(wave * 8 + kbl) * 128;
            a0[kbl] = __hip_atomic_load(Ep + off, __ATOMIC_RELAXED, __HIP_MEMORY_SCOPE_AGENT);
            a1[kbl] = __hip_atomic_load(Ep + off + 1, __ATOMIC_RELAXED, __HIP_MEMORY_SCOPE_AGENT);
        }
        f32x4 C0 = {0.f, 0.f, 0.f, 0.f}, C1 = C0, C2 = C0, C3 = C0;
#pragma unroll
        for (int kbl = 0; kbl < 8; ++kbl) {
            union { unsigned long long u[2]; short8 v; } au;
            au.u[0] = a0[kbl]; au.u[1] = a1[kbl];
            short8 a = au.v;
            C0 = __builtin_amdgcn_mfma_f32_16x16x32_bf16(a, wfrag[0][kbl], C0, 0, 0, 0);
            C1 = __builtin_amdgcn_mfma_f32_16x16x32_bf16(a, wfrag[1][kbl], C1, 0, 0, 0);
            C2 = __builtin_amdgcn_mfma_f32_16x16x32_bf16(a, wfrag[2][kbl], C2, 0, 0, 0);
            C3 = __builtin_amdgcn_mfma_f32_16x16x32_bf16(a, wfrag[3][kbl], C3, 0, 0, 0);
        }
        // D layout: col = lane&15 (j within jsub), row = (lane>>4)*4 + reg (local b)
#pragma unroll
        for (int c = 0; c < 4; ++c) {
            int rb = (q * 4 + c) * 65;
            zred[wave * 1040 + rb + 0 * 16 + jl] = C0[c];
            zred[wave * 1040 + rb + 1 * 16 + jl] = C1[c];
            zred[wave * 1040 + rb + 2 * 16 + jl] = C2[c];
            zred[wave * 1040 + rb + 3 * 16 + jl] = C3[c];
        }
        __syncthreads();
        // Epilogue: thread owns (bl, jbase..jbase+3)
        float4 u4 = *(const float4*)(hidrow + (size_t)t * 1024);
        float hnew[4];
#pragma unroll
        for (int c = 0; c < 4; ++c) {
            int ci = bl * 65 + jq * 4 + c;
            float z = zred[0 * 1040 + ci] + zred[1 * 1040 + ci] +
                      zred[2 * 1040 + ci] + zred[3 * 1040 + ci];
            float rec = fmaxf(z, 0.f) * sgn[c];
            float hn = 0.9f * hold[c] + ALPHA * rec + ((const float*)&u4)[c];
            hold[c] = hn;
            hnew[c] = hn;
        }
        float4 hv; hv.x = hnew[0]; hv.y = hnew[1]; hv.z = hnew[2]; hv.w = hnew[3];
        *(float4*)(hidrow + (size_t)t * 1024) = hv;
        unsigned long long pk = 0;
#pragma unroll
        for (int c = 0; c < 4; ++c)
            pk |= ((unsigned long long)f2bf(sigmoidf_(hnew[c]))) << (16 * c);
        const int p2 = (t + 1) & 1;
        __hip_atomic_store(Ebuf + (size_t)p2 * 16384 + ewoff, pk,
                           __ATOMIC_RELAXED, __HIP_MEMORY_SCOPE_AGENT);
        __syncthreads();   // drains each thread's stores (vmcnt) before flag
        if (tid == 0)
            __hip_atomic_store(flags + (grp * 16 + Jg), (unsigned int)(t + 1),
                               __ATOMIC_RELEASE, __HIP_MEMORY_SCOPE_AGENT);
    }
}

// ---------------------------------------------------------------------------
// K4: logits[bt,o] = sigmoid(hidden[bt,:]) . W_ho[o,:] + b_ho[o]
// Tile 64 bt x 32 o, K chunked by 128. s fp32 in LDS, W_ho bf16 in LDS.
// ---------------------------------------------------------------------------
__global__ __launch_bounds__(256) void k4_logits(
    const float* __restrict__ hidden, const float* __restrict__ Who,
    const float* __restrict__ bho, float* __restrict__ outv) {
    __shared__ float sl[64 * 132];
    __shared__ unsigned short wol[32 * 132];
    const int tid = threadIdx.x;
    const int R0 = blockIdx.x * 64;
    const int O0 = blockIdx.y * 32;
    const int btq = (tid >> 4) * 4;
    const int ob = tid & 15;
    float acc[4][2];
#pragma unroll
    for (int a = 0; a < 4; ++a) { acc[a][0] = 0.f; acc[a][1] = 0.f; }
    for (int kc = 0; kc < 8; ++kc) {
        __syncthreads();
#pragma unroll
        for (int i = 0; i < 8; ++i) {
            int f = i * 1024 + tid * 4;
            int row = f >> 7, col = f & 127;
            float4 v = *(const float4*)(hidden + (size_t)(R0 + row) * 1024 + kc * 128 + col);
            float4 s;
            s.x = sigmoidf_(v.x); s.y = sigmoidf_(v.y);
            s.z = sigmoidf_(v.z); s.w = sigmoidf_(v.w);
            *(float4*)(sl + row * 132 + col) = s;
        }
#pragma unroll
        for (int i = 0; i < 4; ++i) {
            int f = i * 1024 + tid * 4;
            int row = f >> 7, col = f & 127;
            float4 v = *(const float4*)(Who + (size_t)(O0 + row) * 1024 + kc * 128 + col);
            uint2 pk;
            pk.x = (unsigned)f2bf(v.x) | ((unsigned)f2bf(v.y) << 16);
            pk.y = (unsigned)f2bf(v.z) | ((unsigned)f2bf(v.w) << 16);
            *(uint2*)(wol + row * 132 + col) = pk;
        }
        __syncthreads();
        for (int k = 0; k < 128; k += 4) {
            float4 xa[4];
#pragma unroll
            for (int a = 0; a < 4; ++a) xa[a] = *(const float4*)(sl + (btq + a) * 132 + k);
#pragma unroll
            for (int c = 0; c < 2; ++c) {
                uint2 w2 = *(const uint2*)(wol + (ob + 16 * c) * 132 + k);
                float w0 = bf2f((unsigned short)(w2.x & 0xffffu));
                float w1 = bf2f((unsigned short)(w2.x >> 16));
                float w2f = bf2f((unsigned short)(w2.y & 0xffffu));
                float w3 = bf2f((unsigned short)(w2.y >> 16));
#pragma unroll
                for (int a = 0; a < 4; ++a)
                    acc[a][c] += xa[a].x * w0 + xa[a].y * w1 + xa[a].z * w2f + xa[a].w * w3;
            }
        }
    }
#pragma unroll
    for (int c = 0; c < 2; ++c) {
        float bias = bho[O0 + ob + 16 * c];
#pragma unroll
        for (int a = 0; a < 4; ++a) {
            int bt = R0 + btq + a;
            outv[(size_t)bt * 128 + O0 + ob + 16 * c] = acc[a][c] + bias;
        }
    }
}

// ---------------------------------------------------------------------------
// K5: in-place softmax over O=128 per bt-row; one wave per row.
// ---------------------------------------------------------------------------
__global__ __launch_bounds__(256) void k5_softmax(float* __restrict__ outv) {
    const int tid = threadIdx.x;
    const int row = blockIdx.x * 4 + (tid >> 6);
    const int l = tid & 63;
    float* pr = outv + (size_t)row * 128;
    float v0 = pr[l], v1 = pr[l + 64];
    float m = fmaxf(v0, v1);
#pragma unroll
    for (int off = 32; off > 0; off >>= 1) m = fmaxf(m, __shfl_xor(m, off));
    float e0 = __expf(v0 - m), e1 = __expf(v1 - m);
    float s = e0 + e1;
#pragma unroll
    for (int off = 32; off > 0; off >>= 1) s += __shfl_xor(s, off);
    float inv = 1.0f / s;
    pr[l] = e0 * inv;
    pr[l + 64] = e1 * inv;
}

extern "C" void kernel_launch(void* const* d_in, const int* in_sizes, int n_in,
                              void* d_out, int out_size, void* d_ws, size_t ws_size,
                              hipStream_t stream) {
    const float* x     = (const float*)d_in[0];
    const float* h0    = (const float*)d_in[1];
    const float* Wih   = (const float*)d_in[2];
    const float* Whh   = (const float*)d_in[3];
    const float* Who   = (const float*)d_in[4];
    const float* bho   = (const float*)d_in[5];
    const float* sgn   = (const float*)d_in[6];
    const float* noise = (const float*)d_in[7];

    float* outv = (float*)d_out;                               // [32768 x 128]
    float* hidden = outv + (size_t)B_ * S_ * O_;               // [32768 x 1024]

    unsigned long long* Ebuf = (unsigned long long*)d_ws;      // 2 x 128KB
    unsigned int* flags = (unsigned int*)((char*)d_ws + 262144); // 64 flags

    // 1. U = alpha*x@Wih^T + 0.01*noise  (into hidden region, [bt, j])
    k1_precompute_u<<<dim3(512, 16), dim3(256), 0, stream>>>(x, Wih, noise, hidden);
    // 2. init exchange buffer + flags
    k2_init<<<dim3(64), dim3(256), 0, stream>>>(h0, Ebuf, flags);
    // 3. recurrence (cooperative: 64 WGs must be co-resident)
    {
        void* args[] = {(void*)&Whh, (void*)&h0, (void*)&sgn,
                        (void*)&hidden, (void*)&Ebuf, (void*)&flags};
        hipError_t e = hipLaunchCooperativeKernel((const void*)k3_rnn, dim3(64), dim3(256),
                                                  args, 0, stream);
        if (e != hipSuccess) {
            // 64 blocks on 256 CUs: co-resident in practice on an idle device
            k3_rnn<<<dim3(64), dim3(256), 0, stream>>>(Whh, h0, sgn, hidden, Ebuf, flags);
        }
    }
    // 4. logits
    k4_logits<<<dim3(512, 4), dim3(256), 0, stream>>>(hidden, Who, bho, outv);
    // 5. softmax
    k5_softmax<<<dim3(8192), dim3(256), 0, stream>>>(outv);
}

// Round 2
// 1872.019 us; speedup vs baseline: 1.6362x; 1.6362x over previous
//
#include <hip/hip_runtime.h>
#include <hip/hip_bf16.h>

// Problem constants
#define B_ 64
#define S_ 512
#define I_ 128
#define H_ 1024
#define O_ 128
#define ALPHA 0.1f

typedef __attribute__((ext_vector_type(8))) short short8;
typedef __attribute__((ext_vector_type(4))) float f32x4;

__device__ __forceinline__ unsigned short f2bf(float f) {
    unsigned int b = __float_as_uint(f);
    b += 0x7fffu + ((b >> 16) & 1u);   // RNE; inputs are finite
    return (unsigned short)(b >> 16);
}
__device__ __forceinline__ float bf2f(unsigned short u) {
    return __uint_as_float(((unsigned int)u) << 16);
}
__device__ __forceinline__ float sigmoidf_(float v) {
    return 1.0f / (1.0f + __expf(-v));
}

// ---------------------------------------------------------------------------
// K1: U[b,t,j] = ALPHA * (x[b,t,:] . W_ih[j,:]) + 0.01*noise[t,b,j]
// stored into the hidden region of d_out at [bt, j].
// ---------------------------------------------------------------------------
__global__ __launch_bounds__(256) void k1_precompute_u(
    const float* __restrict__ x, const float* __restrict__ Wih,
    const float* __restrict__ noise, float* __restrict__ U) {
    __shared__ float xs[64 * 132];
    __shared__ unsigned short wl[64 * 132];
    const int tid = threadIdx.x;
    const int R0 = blockIdx.x * 64;
    const int J0 = blockIdx.y * 64;
#pragma unroll
    for (int i = 0; i < 8; ++i) {
        int f = i * 1024 + tid * 4;
        float4 v = *(const float4*)(x + (size_t)R0 * 128 + f);
        int row = f >> 7, col = f & 127;
        *(float4*)(xs + row * 132 + col) = v;
    }
#pragma unroll
    for (int i = 0; i < 8; ++i) {
        int f = i * 1024 + tid * 4;
        float4 v = *(const float4*)(Wih + (size_t)J0 * 128 + f);
        int row = f >> 7, col = f & 127;
        uint2 pk;
        pk.x = (unsigned)f2bf(v.x) | ((unsigned)f2bf(v.y) << 16);
        pk.y = (unsigned)f2bf(v.z) | ((unsigned)f2bf(v.w) << 16);
        *(uint2*)(wl + row * 132 + col) = pk;
    }
    __syncthreads();
    const int btq = (tid >> 4) * 4;
    const int jb = tid & 15;
    float acc[4][4];
#pragma unroll
    for (int a = 0; a < 4; ++a)
#pragma unroll
        for (int c = 0; c < 4; ++c) acc[a][c] = 0.f;
    for (int k = 0; k < 128; k += 4) {
        float4 xa[4];
#pragma unroll
        for (int a = 0; a < 4; ++a) xa[a] = *(const float4*)(xs + (btq + a) * 132 + k);
#pragma unroll
        for (int c = 0; c < 4; ++c) {
            uint2 w2 = *(const uint2*)(wl + (jb + 16 * c) * 132 + k);
            float w0 = bf2f((unsigned short)(w2.x & 0xffffu));
            float w1 = bf2f((unsigned short)(w2.x >> 16));
            float w2f = bf2f((unsigned short)(w2.y & 0xffffu));
            float w3 = bf2f((unsigned short)(w2.y >> 16));
#pragma unroll
            for (int a = 0; a < 4; ++a)
                acc[a][c] += xa[a].x * w0 + xa[a].y * w1 + xa[a].z * w2f + xa[a].w * w3;
        }
    }
#pragma unroll
    for (int a = 0; a < 4; ++a) {
        int bt = R0 + btq + a;
        int b = bt >> 9, t = bt & 511;
#pragma unroll
        for (int c = 0; c < 4; ++c) {
            int j = J0 + jb + 16 * c;
            float u = ALPHA * acc[a][c] + 0.01f * noise[((size_t)t * 64 + b) * 1024 + j];
            U[(size_t)bt * 1024 + j] = u;
        }
    }
}

// ---------------------------------------------------------------------------
// K2: init exchange buffer E[0] with swizzled bf16 sigmoid(h0) (phase tag 0).
// E layout (per buffer, per group g): [kb(32)][q(4)][r(16)][i(8)] bf16
//   element (b=g*16+r, k=kb*32+q*8+i). 32KB per group, 128KB per buffer.
// ---------------------------------------------------------------------------
__global__ __launch_bounds__(256) void k2_init(
    const float* __restrict__ h0, unsigned long long* __restrict__ Ebuf) {
    const int tid = threadIdx.x;
    const int b = blockIdx.x;
    const int g = b >> 4, r = b & 15;
    const int k0 = tid * 4;
    const int kb = k0 >> 5, q = (k0 >> 3) & 3, i0 = k0 & 7;
    unsigned long long pk = 0;
#pragma unroll
    for (int j = 0; j < 4; ++j) {
        float s = sigmoidf_(h0[(size_t)b * 1024 + k0 + j]);
        pk |= ((unsigned long long)f2bf(s)) << (16 * j);
    }
    size_t byteoff = (size_t)g * 32768 + (size_t)(kb * 64 + q * 16 + r) * 16 + (size_t)i0 * 2;
    __hip_atomic_store(Ebuf + (byteoff >> 3), pk, __ATOMIC_RELAXED, __HIP_MEMORY_SCOPE_AGENT);
}

// ---------------------------------------------------------------------------
// K3: the recurrence. 64 WGs = 4 batch-groups x 16 j-groups; block 256.
// Each WG: 16 b x 64 j tile. W_hh slice lives in registers as bf16 B-frags.
// Exchange of sigma(h) via global ping-pong, SELF-VALIDATING payload:
// sign bits of each packed bf16 carry phase ((t)>>1)&1 (sigma>0 so sign is
// free). Consumers poll their own data words -> ONE coherence round trip
// per step, no flags, no store-drain barrier. Skew<2 steps is enforced by
// the data dependence itself, so {buffer parity t&1, phase bit} is unique.
// ---------------------------------------------------------------------------
__global__ __launch_bounds__(256, 1) void k3_rnn(
    const float* __restrict__ Whh, const float* __restrict__ h0,
    const float* __restrict__ sgnv, float* __restrict__ hidden,
    unsigned long long* __restrict__ Ebuf) {
    __shared__ float zred[2][4 * 1040];   // ping-pong [wave][b(16) s65][j(64)]
    const int tid = threadIdx.x;
    const int wave = tid >> 6, lane = tid & 63;
    const int wg = blockIdx.x;
    const int grp = wg >> 4;   // batch group 0..3
    const int Jg = wg & 15;    // j group 0..15
    const int jl = lane & 15, q = lane >> 4;

    // Persistent W_hh B-fragments: B[k][n] = Whh[n][k]; n=jl, k=(wave*8+kbl)*32+q*8+i
    short8 wfrag[4][8];
#pragma unroll
    for (int jsub = 0; jsub < 4; ++jsub) {
        int jg = Jg * 64 + jsub * 16 + jl;
#pragma unroll
        for (int kbl = 0; kbl < 8; ++kbl) {
            int k = (wave * 8 + kbl) * 32 + q * 8;
            const float* wp = Whh + (size_t)jg * 1024 + k;
            float4 v0 = *(const float4*)(wp);
            float4 v1 = *(const float4*)(wp + 4);
            short8 f;
            f[0] = (short)f2bf(v0.x); f[1] = (short)f2bf(v0.y);
            f[2] = (short)f2bf(v0.z); f[3] = (short)f2bf(v0.w);
            f[4] = (short)f2bf(v1.x); f[5] = (short)f2bf(v1.y);
            f[6] = (short)f2bf(v1.z); f[7] = (short)f2bf(v1.w);
            wfrag[jsub][kbl] = f;
        }
    }

    // Epilogue ownership: (b = grp*16 + bl, j = Jg*64 + jq*4 + c)
    const int bl = tid & 15;
    const int jq = tid >> 4;
    const int bg = grp * 16 + bl;
    const int jbase = Jg * 64 + jq * 4;
    float hold[4], sgn[4];
#pragma unroll
    for (int c = 0; c < 4; ++c) {
        hold[c] = h0[(size_t)bg * 1024 + jbase + c];
        sgn[c] = sgnv[jbase + c];
    }
    float* hidrow = hidden + (size_t)bg * (512 * 1024) + jbase;

    // E write slot for this thread's 4 consecutive j (= k of next step)
    const int kbw = jbase >> 5;
    const int qqw = (jbase >> 3) & 3;
    const int i0w = jbase & 7;   // 0 or 4
    const size_t ewoff = (((size_t)grp * 32768 +
                           (size_t)(kbw * 64 + qqw * 16 + bl) * 16 + (size_t)i0w * 2) >> 3);

    const size_t eload_base = (size_t)grp * 4096 + (size_t)lane * 2;  // ull units

    // Prefetch U(0)
    float4 u_pref = *(const float4*)(hidrow);

#pragma unroll 1
    for (int t = 0; t < 512; ++t) {
        const int p = t & 1;
        const unsigned long long* Ep = Ebuf + (size_t)p * 16384 + eload_base;
        const unsigned long long es64 = (unsigned long long)((t >> 1) & 1) << 15;
        unsigned long long a0[8], a1[8];
        unsigned int stale = 0xFFFFu;
        for (;;) {
#pragma unroll
            for (int kbl = 0; kbl < 8; ++kbl) {
                size_t off = (size_t)(wave * 8 + kbl) * 128;
                if (stale & (1u << (2 * kbl)))
                    a0[kbl] = __hip_atomic_load(Ep + off, __ATOMIC_RELAXED,
                                                __HIP_MEMORY_SCOPE_AGENT);
                if (stale & (1u << (2 * kbl + 1)))
                    a1[kbl] = __hip_atomic_load(Ep + off + 1, __ATOMIC_RELAXED,
                                                __HIP_MEMORY_SCOPE_AGENT);
            }
            unsigned int ns = 0;
#pragma unroll
            for (int kbl = 0; kbl < 8; ++kbl) {
                ns |= (unsigned int)(((a0[kbl] ^ es64) >> 15) & 1ull) << (2 * kbl);
                ns |= (unsigned int)(((a1[kbl] ^ es64) >> 15) & 1ull) << (2 * kbl + 1);
            }
            stale = ns;
            if (!__any((int)stale)) break;
        }
        f32x4 C0 = {0.f, 0.f, 0.f, 0.f}, C1 = C0, C2 = C0, C3 = C0;
#pragma unroll
        for (int kbl = 0; kbl < 8; ++kbl) {
            union { unsigned long long u[2]; short8 v; } au;
            au.u[0] = a0[kbl] & 0x7fff7fff7fff7fffull;
            au.u[1] = a1[kbl] & 0x7fff7fff7fff7fffull;
            short8 a = au.v;
            C0 = __builtin_amdgcn_mfma_f32_16x16x32_bf16(a, wfrag[0][kbl], C0, 0, 0, 0);
            C1 = __builtin_amdgcn_mfma_f32_16x16x32_bf16(a, wfrag[1][kbl], C1, 0, 0, 0);
            C2 = __builtin_amdgcn_mfma_f32_16x16x32_bf16(a, wfrag[2][kbl], C2, 0, 0, 0);
            C3 = __builtin_amdgcn_mfma_f32_16x16x32_bf16(a, wfrag[3][kbl], C3, 0, 0, 0);
        }
        // D: col = lane&15 (j within jsub), row = (lane>>4)*4 + reg (local b)
        float* zw = &zred[p][0];
#pragma unroll
        for (int c = 0; c < 4; ++c) {
            int rb = (q * 4 + c) * 65;
            zw[wave * 1040 + rb + 0 * 16 + jl] = C0[c];
            zw[wave * 1040 + rb + 1 * 16 + jl] = C1[c];
            zw[wave * 1040 + rb + 2 * 16 + jl] = C2[c];
            zw[wave * 1040 + rb + 3 * 16 + jl] = C3[c];
        }
        __syncthreads();
        float hnew[4];
#pragma unroll
        for (int c = 0; c < 4; ++c) {
            int ci = bl * 65 + jq * 4 + c;
            float z = zw[0 * 1040 + ci] + zw[1 * 1040 + ci] +
                      zw[2 * 1040 + ci] + zw[3 * 1040 + ci];
            float rec = fmaxf(z, 0.f) * sgn[c];
            float hn = 0.9f * hold[c] + ALPHA * rec + ((const float*)&u_pref)[c];
            hold[c] = hn;
            hnew[c] = hn;
        }
        // Pack sigma(hnew) with phase tag ((t+1)>>1)&1 in every sign bit.
        unsigned long long pk = 0;
#pragma unroll
        for (int c = 0; c < 4; ++c)
            pk |= ((unsigned long long)f2bf(sigmoidf_(hnew[c]))) << (16 * c);
        pk |= ((unsigned long long)(((t + 1) >> 1) & 1)) * 0x8000800080008000ull;
        const int p2 = (t + 1) & 1;
        __hip_atomic_store(Ebuf + (size_t)p2 * 16384 + ewoff, pk,
                           __ATOMIC_RELAXED, __HIP_MEMORY_SCOPE_AGENT);
        // hidden(t) write + U(t+1) prefetch (off critical path)
        float4 hv; hv.x = hnew[0]; hv.y = hnew[1]; hv.z = hnew[2]; hv.w = hnew[3];
        *(float4*)(hidrow + (size_t)t * 1024) = hv;
        int tn = (t < 511) ? t + 1 : t;
        u_pref = *(const float4*)(hidrow + (size_t)tn * 1024);
    }
}

// ---------------------------------------------------------------------------
// K4: logits[bt,o] = sigmoid(hidden[bt,:]) . W_ho[o,:] + b_ho[o]
// ---------------------------------------------------------------------------
__global__ __launch_bounds__(256) void k4_logits(
    const float* __restrict__ hidden, const float* __restrict__ Who,
    const float* __restrict__ bho, float* __restrict__ outv) {
    __shared__ float sl[64 * 132];
    __shared__ unsigned short wol[32 * 132];
    const int tid = threadIdx.x;
    const int R0 = blockIdx.x * 64;
    const int O0 = blockIdx.y * 32;
    const int btq = (tid >> 4) * 4;
    const int ob = tid & 15;
    float acc[4][2];
#pragma unroll
    for (int a = 0; a < 4; ++a) { acc[a][0] = 0.f; acc[a][1] = 0.f; }
    for (int kc = 0; kc < 8; ++kc) {
        __syncthreads();
#pragma unroll
        for (int i = 0; i < 8; ++i) {
            int f = i * 1024 + tid * 4;
            int row = f >> 7, col = f & 127;
            float4 v = *(const float4*)(hidden + (size_t)(R0 + row) * 1024 + kc * 128 + col);
            float4 s;
            s.x = sigmoidf_(v.x); s.y = sigmoidf_(v.y);
            s.z = sigmoidf_(v.z); s.w = sigmoidf_(v.w);
            *(float4*)(sl + row * 132 + col) = s;
        }
#pragma unroll
        for (int i = 0; i < 4; ++i) {
            int f = i * 1024 + tid * 4;
            int row = f >> 7, col = f & 127;
            float4 v = *(const float4*)(Who + (size_t)(O0 + row) * 1024 + kc * 128 + col);
            uint2 pk;
            pk.x = (unsigned)f2bf(v.x) | ((unsigned)f2bf(v.y) << 16);
            pk.y = (unsigned)f2bf(v.z) | ((unsigned)f2bf(v.w) << 16);
            *(uint2*)(wol + row * 132 + col) = pk;
        }
        __syncthreads();
        for (int k = 0; k < 128; k += 4) {
            float4 xa[4];
#pragma unroll
            for (int a = 0; a < 4; ++a) xa[a] = *(const float4*)(sl + (btq + a) * 132 + k);
#pragma unroll
            for (int c = 0; c < 2; ++c) {
                uint2 w2 = *(const uint2*)(wol + (ob + 16 * c) * 132 + k);
                float w0 = bf2f((unsigned short)(w2.x & 0xffffu));
                float w1 = bf2f((unsigned short)(w2.x >> 16));
                float w2f = bf2f((unsigned short)(w2.y & 0xffffu));
                float w3 = bf2f((unsigned short)(w2.y >> 16));
#pragma unroll
                for (int a = 0; a < 4; ++a)
                    acc[a][c] += xa[a].x * w0 + xa[a].y * w1 + xa[a].z * w2f + xa[a].w * w3;
            }
        }
    }
#pragma unroll
    for (int c = 0; c < 2; ++c) {
        float bias = bho[O0 + ob + 16 * c];
#pragma unroll
        for (int a = 0; a < 4; ++a) {
            int bt = R0 + btq + a;
            outv[(size_t)bt * 128 + O0 + ob + 16 * c] = acc[a][c] + bias;
        }
    }
}

// ---------------------------------------------------------------------------
// K5: in-place softmax over O=128 per bt-row; one wave per row.
// ---------------------------------------------------------------------------
__global__ __launch_bounds__(256) void k5_softmax(float* __restrict__ outv) {
    const int tid = threadIdx.x;
    const int row = blockIdx.x * 4 + (tid >> 6);
    const int l = tid & 63;
    float* pr = outv + (size_t)row * 128;
    float v0 = pr[l], v1 = pr[l + 64];
    float m = fmaxf(v0, v1);
#pragma unroll
    for (int off = 32; off > 0; off >>= 1) m = fmaxf(m, __shfl_xor(m, off));
    float e0 = __expf(v0 - m), e1 = __expf(v1 - m);
    float s = e0 + e1;
#pragma unroll
    for (int off = 32; off > 0; off >>= 1) s += __shfl_xor(s, off);
    float inv = 1.0f / s;
    pr[l] = e0 * inv;
    pr[l + 64] = e1 * inv;
}

extern "C" void kernel_launch(void* const* d_in, const int* in_sizes, int n_in,
                              void* d_out, int out_size, void* d_ws, size_t ws_size,
                              hipStream_t stream) {
    const float* x     = (const float*)d_in[0];
    const float* h0    = (const float*)d_in[1];
    const float* Wih   = (const float*)d_in[2];
    const float* Whh   = (const float*)d_in[3];
    const float* Who   = (const float*)d_in[4];
    const float* bho   = (const float*)d_in[5];
    const float* sgn   = (const float*)d_in[6];
    const float* noise = (const float*)d_in[7];

    float* outv = (float*)d_out;                               // [32768 x 128]
    float* hidden = outv + (size_t)B_ * S_ * O_;               // [32768 x 1024]

    unsigned long long* Ebuf = (unsigned long long*)d_ws;      // 2 x 128KB

    // 1. U = alpha*x@Wih^T + 0.01*noise  (into hidden region, [bt, j])
    k1_precompute_u<<<dim3(512, 16), dim3(256), 0, stream>>>(x, Wih, noise, hidden);
    // 2. init exchange buffer (phase tag 0)
    k2_init<<<dim3(64), dim3(256), 0, stream>>>(h0, Ebuf);
    // 3. recurrence (cooperative: 64 WGs must be co-resident)
    {
        void* args[] = {(void*)&Whh, (void*)&h0, (void*)&sgn,
                        (void*)&hidden, (void*)&Ebuf};
        hipError_t e = hipLaunchCooperativeKernel((const void*)k3_rnn, dim3(64), dim3(256),
                                                  args, 0, stream);
        if (e != hipSuccess) {
            k3_rnn<<<dim3(64), dim3(256), 0, stream>>>(Whh, h0, sgn, hidden, Ebuf);
        }
    }
    // 4. logits
    k4_logits<<<dim3(512, 4), dim3(256), 0, stream>>>(hidden, Who, bho, outv);
    // 5. softmax
    k5_softmax<<<dim3(8192), dim3(256), 0, stream>>>(outv);
}